// Round 9
// baseline (254.210 us; speedup 1.0000x reference)
//
#include <hip/hip_runtime.h>

#define NN 65536
#define NE 1048576
#define INDIM 512
#define HID 128
#define NB 4096  // edge blocks (NE/256)

typedef __attribute__((ext_vector_type(8))) short bf16x8;
typedef __attribute__((ext_vector_type(16))) float f32x16;

// ---------------- pass 1: per-block LDS histogram over lo8(dst) ----------------
__global__ void k_h1(const int* __restrict__ dst, int* __restrict__ ghist) {
    __shared__ int hcnt[256];
    hcnt[threadIdx.x] = 0;
    __syncthreads();
    int e = blockIdx.x * 256 + threadIdx.x;
    atomicAdd(&hcnt[dst[e] & 255], 1);  // LDS atomic
    __syncthreads();
    ghist[threadIdx.x * NB + blockIdx.x] = hcnt[threadIdx.x];  // bin-major
}

// ---------------- generic 256-wide in-place exclusive scan level ----------------
__global__ void k_scan_ex(int* data, int* bsum, int n) {
    __shared__ int tmp[256];
    int i = blockIdx.x * 256 + threadIdx.x;
    int v = (i < n) ? data[i] : 0;
    tmp[threadIdx.x] = v;
    __syncthreads();
    for (int off = 1; off < 256; off <<= 1) {
        int t = (threadIdx.x >= off) ? tmp[threadIdx.x - off] : 0;
        __syncthreads();
        tmp[threadIdx.x] += t;
        __syncthreads();
    }
    if (i < n) data[i] = tmp[threadIdx.x] - v;  // exclusive
    if (threadIdx.x == 255 && bsum) bsum[blockIdx.x] = tmp[255];
}

// single-block in-place exclusive scan of 4096 ints (replaces 3 kernels)
__global__ void k_scan_mid(int* data) {
    __shared__ int tmp[256];
    __shared__ int carry;
    if (threadIdx.x == 0) carry = 0;
    __syncthreads();
    for (int b = 0; b < 16; b++) {
        int i = b * 256 + threadIdx.x;
        int v = data[i];
        tmp[threadIdx.x] = v;
        __syncthreads();
        for (int off = 1; off < 256; off <<= 1) {
            int t = (threadIdx.x >= off) ? tmp[threadIdx.x - off] : 0;
            __syncthreads();
            tmp[threadIdx.x] += t;
            __syncthreads();
        }
        data[i] = tmp[threadIdx.x] - v + carry;
        __syncthreads();
        if (threadIdx.x == 0) carry += tmp[255];
        __syncthreads();
    }
}

__global__ void k_addback(int* data, const int* __restrict__ bsum) {
    int i = blockIdx.x * 256 + threadIdx.x;
    data[i] += bsum[blockIdx.x];
}

// ---------------- pass 1 scatter: group edges by lo8(dst), LDS cursors only ----------------
__global__ void k_s1(const int* __restrict__ src, const int* __restrict__ dst,
                     const float* __restrict__ ew, const int* __restrict__ ghist,
                     int* __restrict__ e1src, float* __restrict__ e1ew,
                     int* __restrict__ e1dst) {
    __shared__ int cur[256];
    cur[threadIdx.x] = ghist[threadIdx.x * NB + blockIdx.x];  // scanned global base
    __syncthreads();
    int e = blockIdx.x * 256 + threadIdx.x;
    int d = dst[e];
    int p = atomicAdd(&cur[d & 255], 1);  // LDS atomic; region is block-private
    e1src[p] = src[e];
    e1ew[p] = ew[e];
    e1dst[p] = d;
}

// ---------------- pass 2: one block per bin -> final dst-grouped edata + rows + dinv ----------------
__global__ void k_s2(const int* __restrict__ ghist, const int* __restrict__ e1src,
                     const float* __restrict__ e1ew, const int* __restrict__ e1dst,
                     uint2* __restrict__ edata, int* __restrict__ row_beg,
                     int* __restrict__ row_end, float* __restrict__ dinv) {
    __shared__ int cnt[256];
    __shared__ float degs[256];
    __shared__ int tmp[256];
    __shared__ int curx[256];
    const int bin = blockIdx.x;
    const int t = threadIdx.x;
    cnt[t] = 0;
    degs[t] = 0.f;
    __syncthreads();
    const int binstart = ghist[bin * NB];
    const int binend = (bin == 255) ? NE : ghist[(bin + 1) * NB];
    for (int i = binstart + t; i < binend; i += 256) {
        int j = e1dst[i] >> 8;
        atomicAdd(&cnt[j], 1);           // LDS
        atomicAdd(&degs[j], e1ew[i]);    // LDS float
    }
    __syncthreads();
    // exclusive scan of cnt
    int v = cnt[t];
    tmp[t] = v;
    __syncthreads();
    for (int off = 1; off < 256; off <<= 1) {
        int u = (t >= off) ? tmp[t - off] : 0;
        __syncthreads();
        tmp[t] += u;
        __syncthreads();
    }
    int offt = tmp[t] - v;
    int d = (t << 8) | bin;
    int beg = binstart + offt;
    row_beg[d] = beg;
    row_end[d] = beg + v;
    dinv[d] = rsqrtf(1.0f + degs[t]);  // deg >= 1 (self-loop), ew >= 0
    curx[t] = beg;
    __syncthreads();
    for (int i = binstart + t; i < binend; i += 256) {
        int dd = e1dst[i];
        int p = atomicAdd(&curx[dd >> 8], 1);  // LDS; same-dst edges stay contiguous
        edata[p] = make_uint2((unsigned)e1src[i], __float_as_uint(e1ew[i]));
    }
}

// ---------------- fold dinv[src] into edge weight ----------------
__global__ void k_coef(const float* __restrict__ dinv, uint2* edata) {
    int e = blockIdx.x * 256 + threadIdx.x;
    uint2 u = edata[e];
    float c = dinv[u.x] * __uint_as_float(u.y);
    u.y = __float_as_uint(c);
    edata[e] = u;
}

// ---------------- W prep: f32 [K][128] -> MFMA-fragment-packed split-bf16 ----------------
template <int K>
__global__ void k_prep_pack(const float* __restrict__ W, unsigned short* __restrict__ P) {
    int t = blockIdx.x * 256 + threadIdx.x;
    int l = t & 63;
    int h = (t >> 6) & 1;
    int n = (t >> 7) & 3;
    int k0 = t >> 9;
    if (k0 >= K / 16) return;
    int colg = n * 32 + (l & 31);
    int kbase = k0 * 16 + (l >> 5) * 8;
    bf16x8 v;
#pragma unroll
    for (int j = 0; j < 8; j++) {
        float f = W[(size_t)(kbase + j) * 128 + colg];
        unsigned b = __float_as_uint(f);
        if (h == 0) {
            v[j] = (short)(b >> 16);
        } else {
            float lf = f - __uint_as_float(b & 0xFFFF0000u);
            v[j] = (short)(__float_as_uint(lf) >> 16);
        }
    }
    *(bf16x8*)(P + (size_t)t * 8) = v;
}

// ---------------- split-bf16 MFMA GEMM: C[M,128] = A[M,K] @ W[K,128], C in bf16 ----------------
__device__ __forceinline__ void split8(const float4& a0, const float4& a1,
                                       bf16x8& hi, bf16x8& lo) {
    float f[8] = {a0.x, a0.y, a0.z, a0.w, a1.x, a1.y, a1.z, a1.w};
#pragma unroll
    for (int i = 0; i < 8; i++) {
        unsigned b = __float_as_uint(f[i]);
        unsigned hb = b & 0xFFFF0000u;
        float lf = f[i] - __uint_as_float(hb);
        hi[i] = (short)(hb >> 16);
        lo[i] = (short)(__float_as_uint(lf) >> 16);
    }
}

__device__ __forceinline__ unsigned short f2bf_rne(float v) {
    unsigned u = __float_as_uint(v);
    unsigned r = (u + 0x7FFFu + ((u >> 16) & 1u)) >> 16;
    return (unsigned short)r;
}

// Stage one BK=32 chunk (128 rows) into LDS buf: A 16KB + B 16KB, 512 threads.
// A granule g_idx = q*512+tid: kk2lh = g>>8, row = (g>>1)&127, g_st = g&1,
//   g_log = g_st ^ ((row>>2)&1); holds A[row][c*32 + kk2lh*8 + g_log*4 ..+4].
template <int K>
__device__ __forceinline__ void stage_chunk(const float* __restrict__ A, int rowbase,
                                            const unsigned short* __restrict__ Bp,
                                            int c, int tid, float* As, unsigned short* Bs) {
    const int w = tid >> 6;
#pragma unroll
    for (int q = 0; q < 2; ++q) {
        int g_idx = q * 512 + tid;
        int kk2lh = g_idx >> 8;
        int row = (g_idx >> 1) & 127;
        int g = (g_idx & 1) ^ ((row >> 2) & 1);
        const float* src = A + (size_t)(rowbase + row) * K + c * 32 + kk2lh * 8 + g * 4;
        char* dst = (char*)As + (size_t)(q * 512 + w * 64) * 16;
        __builtin_amdgcn_global_load_lds((const __attribute__((address_space(1))) void*)src,
                                         (__attribute__((address_space(3))) void*)dst, 16, 0, 0);
    }
    const char* bsrc0 = (const char*)Bp + (size_t)c * 16384;
#pragma unroll
    for (int q = 0; q < 2; ++q) {
        const char* src = bsrc0 + (size_t)(q * 512 + tid) * 16;
        char* dst = (char*)Bs + (size_t)(q * 512 + w * 64) * 16;
        __builtin_amdgcn_global_load_lds((const __attribute__((address_space(1))) void*)src,
                                         (__attribute__((address_space(3))) void*)dst, 16, 0, 0);
    }
}

// Block: 128 rows x 128 cols, 8 waves (4 row-groups x 2 col-groups), wave tile 32x64.
// Double-buffered LDS, stage(c+1) issued BEFORE compute(c), one barrier per chunk.
template <int K>
__global__ __launch_bounds__(512, 4) void k_gemm_mfma(const float* __restrict__ A,
                                                      const unsigned short* __restrict__ Bp,
                                                      unsigned short* __restrict__ Cb) {
    constexpr int NC = K / 32;
    __shared__ __align__(16) float As[2][4096];            // 2 x 16KB
    __shared__ __align__(16) unsigned short Bs[2][8192];   // 2 x 16KB
    const int tid = threadIdx.x;
    const int w = tid >> 6;
    const int lane = tid & 63;
    const int l31 = lane & 31;
    const int lhalf = lane >> 5;
    const int rowbase = blockIdx.x * 128;
    const int wr = w >> 1;                 // row-group 0..3
    const int ncol = (w & 1) * 2;          // col-tiles ncol, ncol+1
    const int r = wr * 32 + l31;           // row within 128-row tile
    const int xr = (l31 >> 2) & 1;

    f32x16 acc[2] = {};

    stage_chunk<K>(A, rowbase, Bp, 0, tid, As[0], Bs[0]);
    __syncthreads();  // drains vmcnt; buf0 ready

    for (int c = 0; c < NC; ++c) {
        const int cur = c & 1;
        if (c + 1 < NC) stage_chunk<K>(A, rowbase, Bp, c + 1, tid, As[cur ^ 1], Bs[cur ^ 1]);
#pragma unroll
        for (int kk = 0; kk < 2; ++kk) {
            int bg = ((kk * 2 + lhalf) * 128 + r) * 2;
            float4 aa = *(const float4*)&As[cur][(size_t)(bg + xr) * 4];        // k+0..3
            float4 ab = *(const float4*)&As[cur][(size_t)(bg + (1 ^ xr)) * 4];  // k+4..7
            bf16x8 ahi, alo;
            split8(aa, ab, ahi, alo);
#pragma unroll
            for (int n = 0; n < 2; ++n) {
                int f = (ncol + n) * 2;
                bf16x8 bhi = *(const bf16x8*)&Bs[cur][(size_t)((kk * 8 + f) * 64 + lane) * 8];
                bf16x8 blo = *(const bf16x8*)&Bs[cur][(size_t)((kk * 8 + f + 1) * 64 + lane) * 8];
                acc[n] = __builtin_amdgcn_mfma_f32_32x32x16_bf16(ahi, bhi, acc[n], 0, 0, 0);
                acc[n] = __builtin_amdgcn_mfma_f32_32x32x16_bf16(ahi, blo, acc[n], 0, 0, 0);
                acc[n] = __builtin_amdgcn_mfma_f32_32x32x16_bf16(alo, bhi, acc[n], 0, 0, 0);
            }
        }
        __syncthreads();  // next buf staged (vmcnt drained) + all reads of cur done
    }

    const int rbase = rowbase + wr * 32 + 4 * lhalf;
#pragma unroll
    for (int n = 0; n < 2; ++n) {
        const int col = (ncol + n) * 32 + l31;
#pragma unroll
        for (int rr = 0; rr < 16; ++rr) {
            int rout = rbase + (rr & 3) + 8 * (rr >> 2);
            Cb[(size_t)rout * HID + col] = f2bf_rne(acc[n][rr]);
        }
    }
}

// ---------------- aggregation: out[d] = di*(sum c*h[s]) + di^2*h[d] + b (h in bf16) ----------------
__device__ __forceinline__ float2 up2(unsigned u) {
    float2 r;
    r.x = __uint_as_float(u << 16);
    r.y = __uint_as_float(u & 0xFFFF0000u);
    return r;
}

template <bool RELU>
__global__ __launch_bounds__(256) void k_agg(const unsigned short* __restrict__ hb,
                                             const float* __restrict__ dinv,
                                             const int* __restrict__ row_beg,
                                             const int* __restrict__ row_end,
                                             const uint2* __restrict__ edata,
                                             const float* __restrict__ bias,
                                             float* __restrict__ out) {
    int d = (blockIdx.x * blockDim.x + threadIdx.x) >> 6;  // one wave per node
    int lane = threadIdx.x & 63;
    float di = dinv[d];
    float2 hv = up2(((const unsigned*)(hb + (size_t)d * HID))[lane]);
    int beg = row_beg[d], end = row_end[d];
    float ex = 0.f, ey = 0.f;
    int e = beg;
    for (; e + 7 < end; e += 8) {
        uint2 u[8];
        unsigned g[8];
#pragma unroll
        for (int q = 0; q < 8; q++) u[q] = edata[e + q];
#pragma unroll
        for (int q = 0; q < 8; q++) g[q] = ((const unsigned*)(hb + (size_t)u[q].x * HID))[lane];
#pragma unroll
        for (int q = 0; q < 8; q++) {
            float2 vv = up2(g[q]);
            float c = __uint_as_float(u[q].y);
            ex += c * vv.x;
            ey += c * vv.y;
        }
    }
    for (; e < end; ++e) {
        uint2 u = edata[e];
        float2 v = up2(((const unsigned*)(hb + (size_t)u.x * HID))[lane]);
        float c = __uint_as_float(u.y);
        ex += c * v.x;
        ey += c * v.y;
    }
    float2 bv = ((const float2*)bias)[lane];
    float selfc = di * di;
    float ax = di * ex + selfc * hv.x + bv.x;
    float ay = di * ey + selfc * hv.y + bv.y;
    if (RELU) {
        ax = fmaxf(ax, 0.f);
        ay = fmaxf(ay, 0.f);
    }
    float2 rr;
    rr.x = ax;
    rr.y = ay;
    ((float2*)(out + (size_t)d * HID))[lane] = rr;
}

extern "C" void kernel_launch(void* const* d_in, const int* in_sizes, int n_in,
                              void* d_out, int out_size, void* d_ws, size_t ws_size,
                              hipStream_t stream) {
    const float* x = (const float*)d_in[0];
    const int* ei = (const int*)d_in[1];
    const float* ew = (const float*)d_in[2];
    const float* W1 = (const float*)d_in[3];
    const float* b1 = (const float*)d_in[4];
    const float* W2 = (const float*)d_in[5];
    const float* b2 = (const float*)d_in[6];
    const int* src = ei;
    const int* dst = ei + NE;
    float* out = (float*)d_out;

    // Workspace layout — fully disjoint, high-water 43,073,536 B:
    char* ws = (char*)d_ws;
    unsigned short* hb = (unsigned short*)(ws + 0);          // 16 MB bf16 h
    uint2* edata   = (uint2*)(ws + 16777216);                //  8 MB final grouped edges
    int*   ghist   = (int*)(ws + 25165824);                  //  4 MB bin-major histogram
    int*   e1src   = (int*)(ws + 29360128);                  //  4 MB pass-1 src
    float* e1ew    = (float*)(ws + 33554432);                //  4 MB pass-1 ew
    int*   e1dst   = (int*)(ws + 37748736);                  //  4 MB pass-1 dst
    int*   bsum1   = (int*)(ws + 41943040);                  // 16 KB
    int*   row_beg = (int*)(ws + 41960448);                  // 256 KB
    int*   row_end = (int*)(ws + 42222592);                  // 256 KB
    float* dinv    = (float*)(ws + 42484736);                // 256 KB
    unsigned short* bp1 = (unsigned short*)(ws + 42746880);  // 256 KB
    unsigned short* bp2 = (unsigned short*)(ws + 43009024);  //  64 KB

    // CSR build — zero global atomics:
    k_h1<<<NB, 256, 0, stream>>>(dst, ghist);
    k_scan_ex<<<NB, 256, 0, stream>>>(ghist, bsum1, 256 * NB);
    k_scan_mid<<<1, 256, 0, stream>>>(bsum1);
    k_addback<<<NB, 256, 0, stream>>>(ghist, bsum1);
    k_s1<<<NB, 256, 0, stream>>>(src, dst, ew, ghist, e1src, e1ew, e1dst);
    k_s2<<<256, 256, 0, stream>>>(ghist, e1src, e1ew, e1dst, edata, row_beg, row_end, dinv);
    k_coef<<<NB, 256, 0, stream>>>(dinv, edata);
    k_prep_pack<INDIM><<<(INDIM / 16) * 8 * 64 / 256, 256, 0, stream>>>(W1, bp1);
    k_prep_pack<HID><<<(HID / 16) * 8 * 64 / 256, 256, 0, stream>>>(W2, bp2);

    // layer 1: hb = bf16(x @ W1) ; a1 = relu(agg(hb) + b1) -> d_out (f32)
    k_gemm_mfma<INDIM><<<NN / 128, 512, 0, stream>>>(x, bp1, hb);
    k_agg<true><<<NN / 4, 256, 0, stream>>>(hb, dinv, row_beg, row_end, edata, b1, out);

    // layer 2: hb = bf16(a1 @ W2) ; z = agg(hb) + b2 -> d_out (f32)
    k_gemm_mfma<HID><<<NN / 128, 512, 0, stream>>>(out, bp2, hb);
    k_agg<false><<<NN / 4, 256, 0, stream>>>(hb, dinv, row_beg, row_end, edata, b2, out);
}

// Round 10
// 236.203 us; speedup vs baseline: 1.0762x; 1.0762x over previous
//
#include <hip/hip_runtime.h>

#define NN 65536
#define NE 1048576
#define INDIM 512
#define HID 128
#define NB 4096  // edge blocks (NE/256)

typedef __attribute__((ext_vector_type(8))) short bf16x8;
typedef __attribute__((ext_vector_type(16))) float f32x16;

// ---------------- pass 1: per-block LDS histogram over lo8(dst) ----------------
__global__ void k_h1(const int* __restrict__ dst, int* __restrict__ ghist) {
    __shared__ int hcnt[256];
    hcnt[threadIdx.x] = 0;
    __syncthreads();
    int e = blockIdx.x * 256 + threadIdx.x;
    atomicAdd(&hcnt[dst[e] & 255], 1);  // LDS atomic
    __syncthreads();
    ghist[threadIdx.x * NB + blockIdx.x] = hcnt[threadIdx.x];  // bin-major
}

// ---------------- generic 256-wide in-place exclusive scan level ----------------
__global__ void k_scan_ex(int* data, int* bsum, int n) {
    __shared__ int tmp[256];
    int i = blockIdx.x * 256 + threadIdx.x;
    int v = (i < n) ? data[i] : 0;
    tmp[threadIdx.x] = v;
    __syncthreads();
    for (int off = 1; off < 256; off <<= 1) {
        int t = (threadIdx.x >= off) ? tmp[threadIdx.x - off] : 0;
        __syncthreads();
        tmp[threadIdx.x] += t;
        __syncthreads();
    }
    if (i < n) data[i] = tmp[threadIdx.x] - v;  // exclusive
    if (threadIdx.x == 255 && bsum) bsum[blockIdx.x] = tmp[255];
}

__global__ void k_addback(int* data, const int* __restrict__ bsum) {
    int i = blockIdx.x * 256 + threadIdx.x;
    data[i] += bsum[blockIdx.x];
}

// ---------------- pass 1 scatter: group edges by lo8(dst), LDS cursors only ----------------
// packed: e1sd = (dst_hi8 << 16) | src   (src < 2^16)
__global__ void k_s1(const int* __restrict__ src, const int* __restrict__ dst,
                     const float* __restrict__ ew, const int* __restrict__ ghist,
                     unsigned* __restrict__ e1sd, float* __restrict__ e1ew) {
    __shared__ int cur[256];
    cur[threadIdx.x] = ghist[threadIdx.x * NB + blockIdx.x];  // scanned global base
    __syncthreads();
    int e = blockIdx.x * 256 + threadIdx.x;
    int d = dst[e];
    int p = atomicAdd(&cur[d & 255], 1);  // LDS atomic; region is block-private
    e1sd[p] = (unsigned)src[e] | ((unsigned)(d >> 8) << 16);
    e1ew[p] = ew[e];
}

// ---------------- pass 2: one block per bin -> final dst-grouped edata + rows + dinv ----------------
__global__ void k_s2(const int* __restrict__ ghist, const unsigned* __restrict__ e1sd,
                     const float* __restrict__ e1ew,
                     uint2* __restrict__ edata, int* __restrict__ row_beg,
                     int* __restrict__ row_end, float* __restrict__ dinv) {
    __shared__ int cnt[256];
    __shared__ float degs[256];
    __shared__ int tmp[256];
    __shared__ int curx[256];
    const int bin = blockIdx.x;
    const int t = threadIdx.x;
    cnt[t] = 0;
    degs[t] = 0.f;
    __syncthreads();
    const int binstart = ghist[bin * NB];
    const int binend = (bin == 255) ? NE : ghist[(bin + 1) * NB];
    for (int i = binstart + t; i < binend; i += 256) {
        unsigned u = e1sd[i];
        int j = u >> 16;
        atomicAdd(&cnt[j], 1);           // LDS
        atomicAdd(&degs[j], e1ew[i]);    // LDS float
    }
    __syncthreads();
    // exclusive scan of cnt
    int v = cnt[t];
    tmp[t] = v;
    __syncthreads();
    for (int off = 1; off < 256; off <<= 1) {
        int u = (t >= off) ? tmp[t - off] : 0;
        __syncthreads();
        tmp[t] += u;
        __syncthreads();
    }
    int offt = tmp[t] - v;
    int d = (t << 8) | bin;
    int beg = binstart + offt;
    row_beg[d] = beg;
    row_end[d] = beg + v;
    dinv[d] = rsqrtf(1.0f + degs[t]);  // deg >= 1 (self-loop), ew >= 0
    curx[t] = beg;
    __syncthreads();
    for (int i = binstart + t; i < binend; i += 256) {
        unsigned u = e1sd[i];
        int p = atomicAdd(&curx[u >> 16], 1);  // LDS; same-dst edges stay contiguous
        edata[p] = make_uint2(u & 0xFFFFu, __float_as_uint(e1ew[i]));
    }
}

// ---------------- fold dinv[src] into edge weight ----------------
__global__ void k_coef(const float* __restrict__ dinv, uint2* edata) {
    int e = blockIdx.x * 256 + threadIdx.x;
    uint2 u = edata[e];
    float c = dinv[u.x] * __uint_as_float(u.y);
    u.y = __float_as_uint(c);
    edata[e] = u;
}

// ---------------- W prep: f32 [K][128] -> MFMA-fragment-packed split-bf16 ----------------
template <int K>
__global__ void k_prep_pack(const float* __restrict__ W, unsigned short* __restrict__ P) {
    int t = blockIdx.x * 256 + threadIdx.x;
    int l = t & 63;
    int h = (t >> 6) & 1;
    int n = (t >> 7) & 3;
    int k0 = t >> 9;
    if (k0 >= K / 16) return;
    int colg = n * 32 + (l & 31);
    int kbase = k0 * 16 + (l >> 5) * 8;
    bf16x8 v;
#pragma unroll
    for (int j = 0; j < 8; j++) {
        float f = W[(size_t)(kbase + j) * 128 + colg];
        unsigned b = __float_as_uint(f);
        if (h == 0) {
            v[j] = (short)(b >> 16);
        } else {
            float lf = f - __uint_as_float(b & 0xFFFF0000u);
            v[j] = (short)(__float_as_uint(lf) >> 16);
        }
    }
    *(bf16x8*)(P + (size_t)t * 8) = v;
}

// ---------------- split-bf16 MFMA GEMM: C[M,128] = A[M,K] @ W[K,128], C in bf16 ----------------
__device__ __forceinline__ void split8(const float4& a0, const float4& a1,
                                       bf16x8& hi, bf16x8& lo) {
    float f[8] = {a0.x, a0.y, a0.z, a0.w, a1.x, a1.y, a1.z, a1.w};
#pragma unroll
    for (int i = 0; i < 8; i++) {
        unsigned b = __float_as_uint(f[i]);
        unsigned hb = b & 0xFFFF0000u;
        float lf = f[i] - __uint_as_float(hb);
        hi[i] = (short)(hb >> 16);
        lo[i] = (short)(__float_as_uint(lf) >> 16);
    }
}

__device__ __forceinline__ unsigned short f2bf_rne(float v) {
    unsigned u = __float_as_uint(v);
    unsigned r = (u + 0x7FFFu + ((u >> 16) & 1u)) >> 16;
    return (unsigned short)r;
}

// Stage one BK=32 chunk (64 rows) into an LDS buffer: A 8KB + B 16KB, 256 threads.
// Identical mapping to the round-8 proven kernel. L = 6 loads/thread.
template <int K>
__device__ __forceinline__ void stage_chunk(const float* __restrict__ A, int rowbase,
                                            const unsigned short* __restrict__ Bp,
                                            int c, int tid, float* As, unsigned short* Bs) {
    const int w = tid >> 6;
#pragma unroll
    for (int q = 0; q < 2; ++q) {
        int lh = (tid >> 7) & 1;
        int row = (tid >> 1) & 63;
        int g = (tid & 1) ^ ((row >> 2) & 1);
        const float* src = A + (size_t)(rowbase + row) * K + c * 32 + q * 16 + lh * 8 + g * 4;
        char* dst = (char*)As + (size_t)(q * 256 + w * 64) * 16;
        __builtin_amdgcn_global_load_lds((const __attribute__((address_space(1))) void*)src,
                                         (__attribute__((address_space(3))) void*)dst, 16, 0, 0);
    }
    const char* bsrc0 = (const char*)Bp + (size_t)c * 16384;
#pragma unroll
    for (int q = 0; q < 4; ++q) {
        const char* src = bsrc0 + (size_t)(q * 256 + tid) * 16;
        char* dst = (char*)Bs + (size_t)(q * 256 + w * 64) * 16;
        __builtin_amdgcn_global_load_lds((const __attribute__((address_space(1))) void*)src,
                                         (__attribute__((address_space(3))) void*)dst, 16, 0, 0);
    }
}

// Block: 64 rows x 128 cols, 4 waves, wave tile 32x64.
// 3-buffer LDS pipeline with COUNTED vmcnt (never 0 in steady state), raw s_barrier.
// Per iter: barrier(frees buf c-1) -> stage(c+2) -> vmcnt(2L) -> barrier(c ready) -> compute(c).
template <int K>
__global__ __launch_bounds__(256, 2) void k_gemm_mfma(const float* __restrict__ A,
                                                      const unsigned short* __restrict__ Bp,
                                                      unsigned short* __restrict__ Cb) {
    constexpr int NC = K / 32;
    __shared__ __align__(16) float As[3][2048];            // 3 x 8KB
    __shared__ __align__(16) unsigned short Bs[3][8192];   // 3 x 16KB
    const int tid = threadIdx.x;
    const int w = tid >> 6;
    const int lane = tid & 63;
    const int l31 = lane & 31;
    const int lhalf = lane >> 5;
    const int rowbase = blockIdx.x * 64;
    const int ncol = (w & 1) * 2;
    const int r = (w >> 1) * 32 + l31;
    const int xr = (l31 >> 2) & 1;

    f32x16 acc[2] = {};

    stage_chunk<K>(A, rowbase, Bp, 0, tid, As[0], Bs[0]);
    stage_chunk<K>(A, rowbase, Bp, 1, tid, As[1], Bs[1]);

    for (int c = 0; c < NC; ++c) {
        if (c > 0) {
            __builtin_amdgcn_s_barrier();   // all waves done computing chunk c-1 -> buf (c-1)%3 free
            asm volatile("" ::: "memory");
            __builtin_amdgcn_sched_barrier(0);
        }
        if (c + 2 < NC) {
            int b = (c + 2) % 3;
            stage_chunk<K>(A, rowbase, Bp, c + 2, tid, As[b], Bs[b]);
        }
        // wait for chunk c only; chunks c+1 / c+2 stay in flight (L=6 loads/thread each)
        int rem = NC - 1 - c;
        if (rem >= 2)      asm volatile("s_waitcnt vmcnt(12)" ::: "memory");
        else if (rem == 1) asm volatile("s_waitcnt vmcnt(6)" ::: "memory");
        else               asm volatile("s_waitcnt vmcnt(0)" ::: "memory");
        __builtin_amdgcn_s_barrier();       // chunk c visible to all waves
        const int cur = c % 3;
#pragma unroll
        for (int kk = 0; kk < 2; ++kk) {
            int bg = ((kk * 2 + lhalf) * 64 + r) * 2;
            float4 aa = *(const float4*)&As[cur][(size_t)(bg + xr) * 4];        // k+0..3
            float4 ab = *(const float4*)&As[cur][(size_t)(bg + (1 ^ xr)) * 4];  // k+4..7
            bf16x8 ahi, alo;
            split8(aa, ab, ahi, alo);
#pragma unroll
            for (int n = 0; n < 2; ++n) {
                int f = (ncol + n) * 2;
                bf16x8 bhi = *(const bf16x8*)&Bs[cur][(size_t)((kk * 8 + f) * 64 + lane) * 8];
                bf16x8 blo = *(const bf16x8*)&Bs[cur][(size_t)((kk * 8 + f + 1) * 64 + lane) * 8];
                acc[n] = __builtin_amdgcn_mfma_f32_32x32x16_bf16(ahi, bhi, acc[n], 0, 0, 0);
                acc[n] = __builtin_amdgcn_mfma_f32_32x32x16_bf16(ahi, blo, acc[n], 0, 0, 0);
                acc[n] = __builtin_amdgcn_mfma_f32_32x32x16_bf16(alo, bhi, acc[n], 0, 0, 0);
            }
        }
    }

    const int rbase = rowbase + (w >> 1) * 32 + 4 * lhalf;
#pragma unroll
    for (int n = 0; n < 2; ++n) {
        const int col = (ncol + n) * 32 + l31;
#pragma unroll
        for (int rr = 0; rr < 16; ++rr) {
            int rout = rbase + (rr & 3) + 8 * (rr >> 2);
            Cb[(size_t)rout * HID + col] = f2bf_rne(acc[n][rr]);
        }
    }
}

// ---------------- aggregation: out[d] = di*(sum c*h[s]) + di^2*h[d] + b (h in bf16) ----------------
__device__ __forceinline__ float2 up2(unsigned u) {
    float2 r;
    r.x = __uint_as_float(u << 16);
    r.y = __uint_as_float(u & 0xFFFF0000u);
    return r;
}

template <bool RELU>
__global__ __launch_bounds__(256) void k_agg(const unsigned short* __restrict__ hb,
                                             const float* __restrict__ dinv,
                                             const int* __restrict__ row_beg,
                                             const int* __restrict__ row_end,
                                             const uint2* __restrict__ edata,
                                             const float* __restrict__ bias,
                                             float* __restrict__ out) {
    int d = (blockIdx.x * blockDim.x + threadIdx.x) >> 6;  // one wave per node
    int lane = threadIdx.x & 63;
    float di = dinv[d];
    float2 hv = up2(((const unsigned*)(hb + (size_t)d * HID))[lane]);
    int beg = row_beg[d], end = row_end[d];
    float ex = 0.f, ey = 0.f;
    int e = beg;
    for (; e + 7 < end; e += 8) {
        uint2 u[8];
        unsigned g[8];
#pragma unroll
        for (int q = 0; q < 8; q++) u[q] = edata[e + q];
#pragma unroll
        for (int q = 0; q < 8; q++) g[q] = ((const unsigned*)(hb + (size_t)u[q].x * HID))[lane];
#pragma unroll
        for (int q = 0; q < 8; q++) {
            float2 vv = up2(g[q]);
            float c = __uint_as_float(u[q].y);
            ex += c * vv.x;
            ey += c * vv.y;
        }
    }
    for (; e < end; ++e) {
        uint2 u = edata[e];
        float2 v = up2(((const unsigned*)(hb + (size_t)u.x * HID))[lane]);
        float c = __uint_as_float(u.y);
        ex += c * v.x;
        ey += c * v.y;
    }
    float2 bv = ((const float2*)bias)[lane];
    float selfc = di * di;
    float ax = di * ex + selfc * hv.x + bv.x;
    float ay = di * ey + selfc * hv.y + bv.y;
    if (RELU) {
        ax = fmaxf(ax, 0.f);
        ay = fmaxf(ay, 0.f);
    }
    float2 rr;
    rr.x = ax;
    rr.y = ay;
    ((float2*)(out + (size_t)d * HID))[lane] = rr;
}

extern "C" void kernel_launch(void* const* d_in, const int* in_sizes, int n_in,
                              void* d_out, int out_size, void* d_ws, size_t ws_size,
                              hipStream_t stream) {
    const float* x = (const float*)d_in[0];
    const int* ei = (const int*)d_in[1];
    const float* ew = (const float*)d_in[2];
    const float* W1 = (const float*)d_in[3];
    const float* b1 = (const float*)d_in[4];
    const float* W2 = (const float*)d_in[5];
    const float* b2 = (const float*)d_in[6];
    const int* src = ei;
    const int* dst = ei + NE;
    float* out = (float*)d_out;

    // Workspace layout — fully disjoint, high-water 43,073,536 B:
    char* ws = (char*)d_ws;
    unsigned short* hb = (unsigned short*)(ws + 0);          // 16 MB bf16 h
    uint2* edata    = (uint2*)(ws + 16777216);               //  8 MB final grouped edges
    int*   ghist    = (int*)(ws + 25165824);                 //  4 MB bin-major histogram
    unsigned* e1sd  = (unsigned*)(ws + 29360128);            //  4 MB pass-1 packed (dsthi|src)
    float* e1ew     = (float*)(ws + 33554432);               //  4 MB pass-1 ew
    int*   bsum1    = (int*)(ws + 41943040);                 // 16 KB
    int*   bsum2    = (int*)(ws + 41959424);                 //  1 KB
    int*   row_beg  = (int*)(ws + 41960448);                 // 256 KB
    int*   row_end  = (int*)(ws + 42222592);                 // 256 KB
    float* dinv     = (float*)(ws + 42484736);               // 256 KB
    unsigned short* bp1 = (unsigned short*)(ws + 42746880);  // 256 KB
    unsigned short* bp2 = (unsigned short*)(ws + 43009024);  //  64 KB

    // CSR build — zero global atomics:
    k_h1<<<NB, 256, 0, stream>>>(dst, ghist);
    k_scan_ex<<<NB, 256, 0, stream>>>(ghist, bsum1, 256 * NB);
    k_scan_ex<<<16, 256, 0, stream>>>(bsum1, bsum2, NB);
    k_scan_ex<<<1, 256, 0, stream>>>(bsum2, nullptr, 16);
    k_addback<<<16, 256, 0, stream>>>(bsum1, bsum2);
    k_addback<<<NB, 256, 0, stream>>>(ghist, bsum1);
    k_s1<<<NB, 256, 0, stream>>>(src, dst, ew, ghist, e1sd, e1ew);
    k_s2<<<256, 256, 0, stream>>>(ghist, e1sd, e1ew, edata, row_beg, row_end, dinv);
    k_coef<<<NB, 256, 0, stream>>>(dinv, edata);
    k_prep_pack<INDIM><<<(INDIM / 16) * 8 * 64 / 256, 256, 0, stream>>>(W1, bp1);
    k_prep_pack<HID><<<(HID / 16) * 8 * 64 / 256, 256, 0, stream>>>(W2, bp2);

    // layer 1: hb = bf16(x @ W1) ; a1 = relu(agg(hb) + b1) -> d_out (f32)
    k_gemm_mfma<INDIM><<<NN / 64, 256, 0, stream>>>(x, bp1, hb);
    k_agg<true><<<NN / 4, 256, 0, stream>>>(hb, dinv, row_beg, row_end, edata, b1, out);

    // layer 2: hb = bf16(a1 @ W2) ; z = agg(hb) + b2 -> d_out (f32)
    k_gemm_mfma<HID><<<NN / 64, 256, 0, stream>>>(out, bp2, hb);
    k_agg<false><<<NN / 4, 256, 0, stream>>>(hb, dinv, row_beg, row_end, edata, b2, out);
}

// Round 11
// 202.731 us; speedup vs baseline: 1.2539x; 1.1651x over previous
//
#include <hip/hip_runtime.h>

#define NN 65536
#define NE 1048576
#define INDIM 512
#define HID 128
#define NSB 256   // binning blocks (4096 edges each)

typedef __attribute__((ext_vector_type(8))) short bf16x8;
typedef __attribute__((ext_vector_type(16))) float f32x16;

// ---------------- pass 1: per-block LDS histogram over lo8(dst), 4096 edges/block ----------------
__global__ void k_h1(const int* __restrict__ dst, int* __restrict__ ghist) {
    __shared__ int hcnt[256];
    hcnt[threadIdx.x] = 0;
    __syncthreads();
    int base = blockIdx.x * 4096;
#pragma unroll
    for (int r = 0; r < 16; r++)
        atomicAdd(&hcnt[dst[base + r * 256 + threadIdx.x] & 255], 1);  // LDS atomic
    __syncthreads();
    ghist[threadIdx.x * NSB + blockIdx.x] = hcnt[threadIdx.x];  // bin-major [bin][block]
}

// ---------------- generic 256-wide in-place exclusive scan level ----------------
__global__ void k_scan_ex(int* data, int* bsum, int n) {
    __shared__ int tmp[256];
    int i = blockIdx.x * 256 + threadIdx.x;
    int v = (i < n) ? data[i] : 0;
    tmp[threadIdx.x] = v;
    __syncthreads();
    for (int off = 1; off < 256; off <<= 1) {
        int t = (threadIdx.x >= off) ? tmp[threadIdx.x - off] : 0;
        __syncthreads();
        tmp[threadIdx.x] += t;
        __syncthreads();
    }
    if (i < n) data[i] = tmp[threadIdx.x] - v;  // exclusive
    if (threadIdx.x == 255 && bsum) bsum[blockIdx.x] = tmp[255];
}

__global__ void k_addback(int* data, const int* __restrict__ bsum) {
    int i = blockIdx.x * 256 + threadIdx.x;
    data[i] += bsum[blockIdx.x];
}

// ---------------- pass 1 scatter: group edges by lo8(dst), LDS cursors, 4096 edges/block ----------------
// packed: e1sd = (dst_hi8 << 16) | src   (src < 2^16)
__global__ void k_s1(const int* __restrict__ src, const int* __restrict__ dst,
                     const float* __restrict__ ew, const int* __restrict__ ghist,
                     unsigned* __restrict__ e1sd, float* __restrict__ e1ew) {
    __shared__ int cur[256];
    cur[threadIdx.x] = ghist[threadIdx.x * NSB + blockIdx.x];  // scanned global base
    __syncthreads();
    int base = blockIdx.x * 4096;
#pragma unroll
    for (int r = 0; r < 16; r++) {
        int e = base + r * 256 + threadIdx.x;
        int d = dst[e];
        int p = atomicAdd(&cur[d & 255], 1);  // LDS atomic; (block,bin) region private
        e1sd[p] = (unsigned)src[e] | ((unsigned)(d >> 8) << 16);
        e1ew[p] = ew[e];
    }
}

// ---------------- pass 2: one block per bin -> final dst-grouped edata + rows + dinv ----------------
__global__ void k_s2(const int* __restrict__ ghist, const unsigned* __restrict__ e1sd,
                     const float* __restrict__ e1ew,
                     uint2* __restrict__ edata, int* __restrict__ row_beg,
                     int* __restrict__ row_end, float* __restrict__ dinv) {
    __shared__ int cnt[256];
    __shared__ float degs[256];
    __shared__ int tmp[256];
    __shared__ int curx[256];
    const int bin = blockIdx.x;
    const int t = threadIdx.x;
    cnt[t] = 0;
    degs[t] = 0.f;
    __syncthreads();
    const int binstart = ghist[bin * NSB];
    const int binend = (bin == 255) ? NE : ghist[(bin + 1) * NSB];
    for (int i = binstart + t; i < binend; i += 256) {
        unsigned u = e1sd[i];
        int j = u >> 16;
        atomicAdd(&cnt[j], 1);           // LDS
        atomicAdd(&degs[j], e1ew[i]);    // LDS float
    }
    __syncthreads();
    // exclusive scan of cnt
    int v = cnt[t];
    tmp[t] = v;
    __syncthreads();
    for (int off = 1; off < 256; off <<= 1) {
        int u = (t >= off) ? tmp[t - off] : 0;
        __syncthreads();
        tmp[t] += u;
        __syncthreads();
    }
    int offt = tmp[t] - v;
    int d = (t << 8) | bin;
    int beg = binstart + offt;
    row_beg[d] = beg;
    row_end[d] = beg + v;
    dinv[d] = rsqrtf(1.0f + degs[t]);  // deg >= 1 (self-loop), ew >= 0
    curx[t] = beg;
    __syncthreads();
    for (int i = binstart + t; i < binend; i += 256) {
        unsigned u = e1sd[i];
        int p = atomicAdd(&curx[u >> 16], 1);  // LDS; same-dst edges stay contiguous
        edata[p] = make_uint2(u & 0xFFFFu, __float_as_uint(e1ew[i]));  // raw ew; dinv folded in agg
    }
}

// ---------------- W prep: f32 [K][128] -> MFMA-fragment-packed split-bf16 ----------------
template <int K>
__global__ void k_prep_pack(const float* __restrict__ W, unsigned short* __restrict__ P) {
    int t = blockIdx.x * 256 + threadIdx.x;
    int l = t & 63;
    int h = (t >> 6) & 1;
    int n = (t >> 7) & 3;
    int k0 = t >> 9;
    if (k0 >= K / 16) return;
    int colg = n * 32 + (l & 31);
    int kbase = k0 * 16 + (l >> 5) * 8;
    bf16x8 v;
#pragma unroll
    for (int j = 0; j < 8; j++) {
        float f = W[(size_t)(kbase + j) * 128 + colg];
        unsigned b = __float_as_uint(f);
        if (h == 0) {
            v[j] = (short)(b >> 16);
        } else {
            float lf = f - __uint_as_float(b & 0xFFFF0000u);
            v[j] = (short)(__float_as_uint(lf) >> 16);
        }
    }
    *(bf16x8*)(P + (size_t)t * 8) = v;
}

// ---------------- split-bf16 MFMA GEMM: C[M,128] = A[M,K] @ W[K,128], C in bf16 ----------------
__device__ __forceinline__ void split8(const float4& a0, const float4& a1,
                                       bf16x8& hi, bf16x8& lo) {
    float f[8] = {a0.x, a0.y, a0.z, a0.w, a1.x, a1.y, a1.z, a1.w};
#pragma unroll
    for (int i = 0; i < 8; i++) {
        unsigned b = __float_as_uint(f[i]);
        unsigned hb = b & 0xFFFF0000u;
        float lf = f[i] - __uint_as_float(hb);
        hi[i] = (short)(hb >> 16);
        lo[i] = (short)(__float_as_uint(lf) >> 16);
    }
}

__device__ __forceinline__ unsigned short f2bf_rne(float v) {
    unsigned u = __float_as_uint(v);
    unsigned r = (u + 0x7FFFu + ((u >> 16) & 1u)) >> 16;
    return (unsigned short)r;
}

// Stage one BK=32 chunk (64 rows) into an LDS buffer: A 8KB + B 16KB, 256 threads. L=6 loads/thread.
template <int K>
__device__ __forceinline__ void stage_chunk(const float* __restrict__ A, int rowbase,
                                            const unsigned short* __restrict__ Bp,
                                            int c, int tid, float* As, unsigned short* Bs) {
    const int w = tid >> 6;
#pragma unroll
    for (int q = 0; q < 2; ++q) {
        int lh = (tid >> 7) & 1;
        int row = (tid >> 1) & 63;
        int g = (tid & 1) ^ ((row >> 2) & 1);
        const float* src = A + (size_t)(rowbase + row) * K + c * 32 + q * 16 + lh * 8 + g * 4;
        char* dst = (char*)As + (size_t)(q * 256 + w * 64) * 16;
        __builtin_amdgcn_global_load_lds((const __attribute__((address_space(1))) void*)src,
                                         (__attribute__((address_space(3))) void*)dst, 16, 0, 0);
    }
    const char* bsrc0 = (const char*)Bp + (size_t)c * 16384;
#pragma unroll
    for (int q = 0; q < 4; ++q) {
        const char* src = bsrc0 + (size_t)(q * 256 + tid) * 16;
        char* dst = (char*)Bs + (size_t)(q * 256 + w * 64) * 16;
        __builtin_amdgcn_global_load_lds((const __attribute__((address_space(1))) void*)src,
                                         (__attribute__((address_space(3))) void*)dst, 16, 0, 0);
    }
}

// Block: 64 rows x 128 cols, 4 waves, wave tile 32x64.
// 3-buffer LDS pipeline with COUNTED vmcnt (never 0 in steady state), raw s_barrier.
template <int K>
__global__ __launch_bounds__(256, 2) void k_gemm_mfma(const float* __restrict__ A,
                                                      const unsigned short* __restrict__ Bp,
                                                      unsigned short* __restrict__ Cb) {
    constexpr int NC = K / 32;
    __shared__ __align__(16) float As[3][2048];            // 3 x 8KB
    __shared__ __align__(16) unsigned short Bs[3][8192];   // 3 x 16KB
    const int tid = threadIdx.x;
    const int w = tid >> 6;
    const int lane = tid & 63;
    const int l31 = lane & 31;
    const int lhalf = lane >> 5;
    const int rowbase = blockIdx.x * 64;
    const int ncol = (w & 1) * 2;
    const int r = (w >> 1) * 32 + l31;
    const int xr = (l31 >> 2) & 1;

    f32x16 acc[2] = {};

    stage_chunk<K>(A, rowbase, Bp, 0, tid, As[0], Bs[0]);
    stage_chunk<K>(A, rowbase, Bp, 1, tid, As[1], Bs[1]);

    for (int c = 0; c < NC; ++c) {
        if (c > 0) {
            __builtin_amdgcn_s_barrier();   // all waves done computing chunk c-1 -> buf (c-1)%3 free
            asm volatile("" ::: "memory");
            __builtin_amdgcn_sched_barrier(0);
        }
        if (c + 2 < NC) {
            int b = (c + 2) % 3;
            stage_chunk<K>(A, rowbase, Bp, c + 2, tid, As[b], Bs[b]);
        }
        int rem = NC - 1 - c;
        if (rem >= 2)      asm volatile("s_waitcnt vmcnt(12)" ::: "memory");
        else if (rem == 1) asm volatile("s_waitcnt vmcnt(6)" ::: "memory");
        else               asm volatile("s_waitcnt vmcnt(0)" ::: "memory");
        __builtin_amdgcn_s_barrier();       // chunk c visible to all waves
        const int cur = c % 3;
#pragma unroll
        for (int kk = 0; kk < 2; ++kk) {
            int bg = ((kk * 2 + lhalf) * 64 + r) * 2;
            float4 aa = *(const float4*)&As[cur][(size_t)(bg + xr) * 4];        // k+0..3
            float4 ab = *(const float4*)&As[cur][(size_t)(bg + (1 ^ xr)) * 4];  // k+4..7
            bf16x8 ahi, alo;
            split8(aa, ab, ahi, alo);
#pragma unroll
            for (int n = 0; n < 2; ++n) {
                int f = (ncol + n) * 2;
                bf16x8 bhi = *(const bf16x8*)&Bs[cur][(size_t)((kk * 8 + f) * 64 + lane) * 8];
                bf16x8 blo = *(const bf16x8*)&Bs[cur][(size_t)((kk * 8 + f + 1) * 64 + lane) * 8];
                acc[n] = __builtin_amdgcn_mfma_f32_32x32x16_bf16(ahi, bhi, acc[n], 0, 0, 0);
                acc[n] = __builtin_amdgcn_mfma_f32_32x32x16_bf16(ahi, blo, acc[n], 0, 0, 0);
                acc[n] = __builtin_amdgcn_mfma_f32_32x32x16_bf16(alo, bhi, acc[n], 0, 0, 0);
            }
        }
    }

    const int rbase = rowbase + (w >> 1) * 32 + 4 * lhalf;
#pragma unroll
    for (int n = 0; n < 2; ++n) {
        const int col = (ncol + n) * 32 + l31;
#pragma unroll
        for (int rr = 0; rr < 16; ++rr) {
            int rout = rbase + (rr & 3) + 8 * (rr >> 2);
            Cb[(size_t)rout * HID + col] = f2bf_rne(acc[n][rr]);
        }
    }
}

// ---------------- aggregation: out[d] = di*(sum dinv[s]*ew*h[s]) + di^2*h[d] + b ----------------
__device__ __forceinline__ float2 up2(unsigned u) {
    float2 r;
    r.x = __uint_as_float(u << 16);
    r.y = __uint_as_float(u & 0xFFFF0000u);
    return r;
}

template <bool RELU>
__global__ __launch_bounds__(256) void k_agg(const unsigned short* __restrict__ hb,
                                             const float* __restrict__ dinv,
                                             const int* __restrict__ row_beg,
                                             const int* __restrict__ row_end,
                                             const uint2* __restrict__ edata,
                                             const float* __restrict__ bias,
                                             float* __restrict__ out) {
    int d = (blockIdx.x * blockDim.x + threadIdx.x) >> 6;  // one wave per node
    int lane = threadIdx.x & 63;
    float di = dinv[d];
    float2 hv = up2(((const unsigned*)(hb + (size_t)d * HID))[lane]);
    int beg = row_beg[d], end = row_end[d];
    float ex = 0.f, ey = 0.f;
    int e = beg;
    for (; e + 15 < end; e += 16) {
        uint2 u[16];
        unsigned g[16];
        float dv[16];
#pragma unroll
        for (int q = 0; q < 16; q++) u[q] = edata[e + q];
#pragma unroll
        for (int q = 0; q < 16; q++) {
            g[q] = ((const unsigned*)(hb + (size_t)u[q].x * HID))[lane];
            dv[q] = dinv[u[q].x];
        }
#pragma unroll
        for (int q = 0; q < 16; q++) {
            float2 vv = up2(g[q]);
            float c = dv[q] * __uint_as_float(u[q].y);
            ex += c * vv.x;
            ey += c * vv.y;
        }
    }
    for (; e + 3 < end; e += 4) {
        uint2 u[4];
        unsigned g[4];
        float dv[4];
#pragma unroll
        for (int q = 0; q < 4; q++) u[q] = edata[e + q];
#pragma unroll
        for (int q = 0; q < 4; q++) {
            g[q] = ((const unsigned*)(hb + (size_t)u[q].x * HID))[lane];
            dv[q] = dinv[u[q].x];
        }
#pragma unroll
        for (int q = 0; q < 4; q++) {
            float2 vv = up2(g[q]);
            float c = dv[q] * __uint_as_float(u[q].y);
            ex += c * vv.x;
            ey += c * vv.y;
        }
    }
    for (; e < end; ++e) {
        uint2 u = edata[e];
        float2 v = up2(((const unsigned*)(hb + (size_t)u.x * HID))[lane]);
        float c = dinv[u.x] * __uint_as_float(u.y);
        ex += c * v.x;
        ey += c * v.y;
    }
    float2 bv = ((const float2*)bias)[lane];
    float selfc = di * di;
    float ax = di * ex + selfc * hv.x + bv.x;
    float ay = di * ey + selfc * hv.y + bv.y;
    if (RELU) {
        ax = fmaxf(ax, 0.f);
        ay = fmaxf(ay, 0.f);
    }
    float2 rr;
    rr.x = ax;
    rr.y = ay;
    ((float2*)(out + (size_t)d * HID))[lane] = rr;
}

extern "C" void kernel_launch(void* const* d_in, const int* in_sizes, int n_in,
                              void* d_out, int out_size, void* d_ws, size_t ws_size,
                              hipStream_t stream) {
    const float* x = (const float*)d_in[0];
    const int* ei = (const int*)d_in[1];
    const float* ew = (const float*)d_in[2];
    const float* W1 = (const float*)d_in[3];
    const float* b1 = (const float*)d_in[4];
    const float* W2 = (const float*)d_in[5];
    const float* b2 = (const float*)d_in[6];
    const int* src = ei;
    const int* dst = ei + NE;
    float* out = (float*)d_out;

    // Workspace layout — fully disjoint, high-water ~34.9 MB:
    char* ws = (char*)d_ws;
    unsigned short* hb = (unsigned short*)(ws + 0);          // 16 MB bf16 h
    uint2* edata    = (uint2*)(ws + 16777216);               //  8 MB final grouped edges
    int*   ghist    = (int*)(ws + 25165824);                 // 256 KB [256 bins][256 blocks]
    int*   bsum1    = (int*)(ws + 25427968);                 //  1 KB
    unsigned* e1sd  = (unsigned*)(ws + 25428992);            //  4 MB pass-1 packed (dsthi|src)
    float* e1ew     = (float*)(ws + 29623296);               //  4 MB pass-1 ew
    int*   row_beg  = (int*)(ws + 33817600);                 // 256 KB
    int*   row_end  = (int*)(ws + 34079744);                 // 256 KB
    float* dinv     = (float*)(ws + 34341888);               // 256 KB
    unsigned short* bp1 = (unsigned short*)(ws + 34604032);  // 256 KB
    unsigned short* bp2 = (unsigned short*)(ws + 34866176);  //  64 KB

    // CSR build — zero global atomics, coarse (4096-edge) binning blocks:
    k_h1<<<NSB, 256, 0, stream>>>(dst, ghist);
    k_scan_ex<<<NSB, 256, 0, stream>>>(ghist, bsum1, 256 * NSB);
    k_scan_ex<<<1, 256, 0, stream>>>(bsum1, nullptr, NSB);
    k_addback<<<NSB, 256, 0, stream>>>(ghist, bsum1);
    k_s1<<<NSB, 256, 0, stream>>>(src, dst, ew, ghist, e1sd, e1ew);
    k_s2<<<256, 256, 0, stream>>>(ghist, e1sd, e1ew, edata, row_beg, row_end, dinv);
    k_prep_pack<INDIM><<<(INDIM / 16) * 8 * 64 / 256, 256, 0, stream>>>(W1, bp1);
    k_prep_pack<HID><<<(HID / 16) * 8 * 64 / 256, 256, 0, stream>>>(W2, bp2);

    // layer 1: hb = bf16(x @ W1) ; a1 = relu(agg(hb) + b1) -> d_out (f32)
    k_gemm_mfma<INDIM><<<NN / 64, 256, 0, stream>>>(x, bp1, hb);
    k_agg<true><<<NN / 4, 256, 0, stream>>>(hb, dinv, row_beg, row_end, edata, b1, out);

    // layer 2: hb = bf16(a1 @ W2) ; z = agg(hb) + b2 -> d_out (f32)
    k_gemm_mfma<HID><<<NN / 64, 256, 0, stream>>>(out, bp2, hb);
    k_agg<false><<<NN / 4, 256, 0, stream>>>(hb, dinv, row_beg, row_end, edata, b2, out);
}